// Round 1
// baseline (699.096 us; speedup 1.0000x reference)
//
#include <hip/hip_runtime.h>
#include <stdint.h>

#define NTOK 16384
#define DIM  1024
#define ODIM 1024
#define NEXP 8

typedef float  f32x4  __attribute__((ext_vector_type(4)));
typedef __bf16 bf16x8 __attribute__((ext_vector_type(8)));
typedef short  s16x8  __attribute__((ext_vector_type(8)));

__device__ __forceinline__ uint16_t f2bf(float f) {
  uint32_t u = __builtin_bit_cast(uint32_t, f);
  u += 0x7fffu + ((u >> 16) & 1u);
  return (uint16_t)(u >> 16);
}

__device__ __forceinline__ void gload_lds16(const void* g, void* l) {
  __builtin_amdgcn_global_load_lds(
      (const __attribute__((address_space(1))) uint32_t*)g,
      (__attribute__((address_space(3))) uint32_t*)l, 16, 0, 0);
}

// ---------------- Kernel 1: gate (fp32) + route + x -> bf16 ----------------
__global__ __launch_bounds__(256) void gate_kernel(
    const float* __restrict__ x, const float* __restrict__ gate_w,
    const float* __restrict__ gate_b, uint16_t* __restrict__ xb,
    int* __restrict__ cnt0, int* __restrict__ cnt1,
    int* __restrict__ tok0, int* __restrict__ tok1,
    float* __restrict__ pr0, float* __restrict__ pr1) {
  __shared__ float gw[DIM * 9];   // pad stride 9 -> conflict-free lane reads
  const int tid = threadIdx.x;
#pragma unroll
  for (int i = 0; i < 32; ++i) {
    int idx = i * 256 + tid;          // 1024*8 elements
    int d = idx >> 3, e = idx & 7;
    gw[d * 9 + e] = gate_w[idx];
  }
  __syncthreads();
  const int wave = tid >> 6, lane = tid & 63;
  float gb[8];
#pragma unroll
  for (int e = 0; e < 8; ++e) gb[e] = gate_b[e];

  for (int t = 0; t < 16; ++t) {
    const int n = blockIdx.x * 64 + wave * 16 + t;
    float s[8] = {0.f, 0.f, 0.f, 0.f, 0.f, 0.f, 0.f, 0.f};
#pragma unroll
    for (int j = 0; j < 16; ++j) {
      int d = j * 64 + lane;
      float xv = x[(size_t)n * DIM + d];
      xb[(size_t)n * DIM + d] = f2bf(xv);
#pragma unroll
      for (int e = 0; e < 8; ++e) s[e] += xv * gw[d * 9 + e];
    }
#pragma unroll
    for (int e = 0; e < 8; ++e) {
      float v = s[e];
      for (int m = 1; m < 64; m <<= 1) v += __shfl_xor(v, m);
      s[e] = v + gb[e];
    }
    // top-2 (strict > keeps lowest index on ties, matches lax.top_k)
    float v1 = -1e30f; int i1 = 0;
#pragma unroll
    for (int e = 0; e < 8; ++e) if (s[e] > v1) { v1 = s[e]; i1 = e; }
    float v2 = -1e30f; int i2 = -1;
#pragma unroll
    for (int e = 0; e < 8; ++e) if (e != i1 && s[e] > v2) { v2 = s[e]; i2 = e; }
    float ssum = 0.f;
#pragma unroll
    for (int e = 0; e < 8; ++e) ssum += expf(s[e] - v1);
    float p1 = 1.0f / ssum;                 // expf(v1-v1)=1
    float p2 = expf(v2 - v1) / ssum;
    if (lane == 0) {
      int pos0 = atomicAdd(&cnt0[i1], 1);
      tok0[i1 * NTOK + pos0] = n;  pr0[i1 * NTOK + pos0] = p1;
      int pos1 = atomicAdd(&cnt1[i2], 1);
      tok1[i2 * NTOK + pos1] = n;  pr1[i2 * NTOK + pos1] = p2;
    }
  }
}

// ------------- Kernel 2: expert_w [E][D][O] fp32 -> wt [E][O][D] bf16 -------------
__global__ __launch_bounds__(256) void wcast_kernel(
    const float* __restrict__ ew, uint16_t* __restrict__ wt) {
  __shared__ uint16_t tile[64][65];
  const int e = blockIdx.z;
  const int db = blockIdx.y * 64, ob = blockIdx.x * 64;
  const int t = threadIdx.x, c = t & 63, r4 = t >> 6;
#pragma unroll
  for (int i = 0; i < 16; ++i) {
    int d = db + i * 4 + r4;
    tile[i * 4 + r4][c] = f2bf(ew[((size_t)e * DIM + d) * ODIM + ob + c]);
  }
  __syncthreads();
#pragma unroll
  for (int i = 0; i < 16; ++i) {
    int o = ob + i * 4 + r4;
    wt[((size_t)e * ODIM + o) * DIM + db + c] = tile[c][i * 4 + r4];
  }
}

// ---------------- Kernel 3: grouped GEMM, 128x128x32 bf16 MFMA ----------------
// pass ACCUM=0: out[tok] = p*(x@W+b) ; ACCUM=1: out[tok] += p*(x@W+b)
template <int ACCUM>
__global__ __launch_bounds__(256) void moe_gemm(
    const uint16_t* __restrict__ xb, const uint16_t* __restrict__ wt,
    const float* __restrict__ eb, const int* __restrict__ cnt,
    const int* __restrict__ tok, const float* __restrict__ pr,
    float* __restrict__ out) {
  __shared__ __align__(16) uint16_t sA[128 * 32];
  __shared__ __align__(16) uint16_t sB[128 * 32];
  __shared__ int   tokl[128];
  __shared__ float pl[128];

  // map blockIdx.y -> (expert, m-block) via counts
  const int by = blockIdx.y;
  int e_sel = -1, m0 = 0, cnt_e = 0, run = 0;
#pragma unroll
  for (int e = 0; e < 8; ++e) {
    int c = cnt[e];
    int nb = (c + 127) >> 7;
    if (e_sel < 0 && by < run + nb) { e_sel = e; m0 = (by - run) << 7; cnt_e = c; }
    run += nb;
  }
  if (e_sel < 0) return;
  const int n0  = blockIdx.x * 128;
  const int tid = threadIdx.x;

  if (tid < 128) {
    int idx = m0 + tid;
    int valid = idx < cnt_e;
    tokl[tid] = valid ? tok[e_sel * NTOK + idx] : 0;
    pl[tid]   = valid ? pr[e_sel * NTOK + idx] : 0.f;
  }
  __syncthreads();

  const int wave = tid >> 6, lane = tid & 63;
  const int kc8 = (tid & 3) * 8;
  const uint16_t* srcA0 = xb + (size_t)tokl[tid >> 2] * DIM + kc8;
  const uint16_t* srcA1 = xb + (size_t)tokl[64 + (tid >> 2)] * DIM + kc8;
  const uint16_t* srcB0 = wt + ((size_t)e_sel * ODIM + n0 + (tid >> 2)) * DIM + kc8;
  const uint16_t* srcB1 = srcB0 + (size_t)64 * DIM;
  char* ldsA0 = (char*)sA + wave * 1024;
  char* ldsA1 = (char*)sA + 4096 + wave * 1024;
  char* ldsB0 = (char*)sB + wave * 1024;
  char* ldsB1 = (char*)sB + 4096 + wave * 1024;

  f32x4 acc[4][4] = {};
  const int wm = (wave & 1) * 64, wn = (wave >> 1) * 64;
  const int ro = lane >> 4, cl = lane & 15;

  for (int k0 = 0; k0 < DIM; k0 += 32) {
    gload_lds16(srcA0, ldsA0);
    gload_lds16(srcA1, ldsA1);
    gload_lds16(srcB0, ldsB0);
    gload_lds16(srcB1, ldsB1);
    srcA0 += 32; srcA1 += 32; srcB0 += 32; srcB1 += 32;
    __syncthreads();   // vmcnt(0) drain -> LDS tiles ready

    s16x8 a_[4], b_[4];
#pragma unroll
    for (int m = 0; m < 4; ++m)
      a_[m] = *reinterpret_cast<const s16x8*>(&sA[(wm + m * 16 + cl) * 32 + ro * 8]);
#pragma unroll
    for (int n = 0; n < 4; ++n)
      b_[n] = *reinterpret_cast<const s16x8*>(&sB[(wn + n * 16 + cl) * 32 + ro * 8]);
#pragma unroll
    for (int m = 0; m < 4; ++m)
#pragma unroll
      for (int n = 0; n < 4; ++n)
        acc[m][n] = __builtin_amdgcn_mfma_f32_16x16x32_bf16(
            __builtin_bit_cast(bf16x8, a_[m]), __builtin_bit_cast(bf16x8, b_[n]),
            acc[m][n], 0, 0, 0);
    __syncthreads();   // protect LDS before next stage
  }

  // epilogue: D row = ro*4+i, col = cl (m89-verified C/D layout)
#pragma unroll
  for (int n = 0; n < 4; ++n) {
    const int col = n0 + wn + n * 16 + cl;
    const float bias = eb[e_sel * ODIM + col];
#pragma unroll
    for (int m = 0; m < 4; ++m) {
#pragma unroll
      for (int i = 0; i < 4; ++i) {
        const int rl = wm + m * 16 + ro * 4 + i;
        if (m0 + rl < cnt_e) {
          const float v = pl[rl] * (acc[m][n][i] + bias);
          const size_t oidx = (size_t)tokl[rl] * ODIM + col;
          if (ACCUM) out[oidx] += v; else out[oidx] = v;
        }
      }
    }
  }
}

// ------------------------------- launcher -------------------------------
extern "C" void kernel_launch(void* const* d_in, const int* in_sizes, int n_in,
                              void* d_out, int out_size, void* d_ws, size_t ws_size,
                              hipStream_t stream) {
  const float* x      = (const float*)d_in[0];
  const float* gate_w = (const float*)d_in[1];
  const float* gate_b = (const float*)d_in[2];
  const float* ew     = (const float*)d_in[3];
  const float* eb     = (const float*)d_in[4];
  float* out = (float*)d_out;

  char* ws = (char*)d_ws;
  size_t off = 0;
  uint16_t* xb = (uint16_t*)(ws + off); off += (size_t)NTOK * DIM * 2;       // 32 MB
  uint16_t* wt = (uint16_t*)(ws + off); off += (size_t)NEXP * DIM * ODIM * 2; // 16 MB
  int*   tok0 = (int*)(ws + off);   off += (size_t)NEXP * NTOK * 4;
  int*   tok1 = (int*)(ws + off);   off += (size_t)NEXP * NTOK * 4;
  float* pr0  = (float*)(ws + off); off += (size_t)NEXP * NTOK * 4;
  float* pr1  = (float*)(ws + off); off += (size_t)NEXP * NTOK * 4;
  int*   cnt0 = (int*)(ws + off);   off += 32;
  int*   cnt1 = (int*)(ws + off);   off += 32;

  hipMemsetAsync(cnt0, 0, 64, stream);  // zeros cnt0[8] + cnt1[8]

  gate_kernel<<<NTOK / 64, 256, 0, stream>>>(x, gate_w, gate_b, xb,
                                             cnt0, cnt1, tok0, tok1, pr0, pr1);
  wcast_kernel<<<dim3(16, 16, 8), 256, 0, stream>>>(ew, wt);
  moe_gemm<0><<<dim3(8, 136), 256, 0, stream>>>(xb, wt, eb, cnt0, tok0, pr0, out);
  moe_gemm<1><<<dim3(8, 136), 256, 0, stream>>>(xb, wt, eb, cnt1, tok1, pr1, out);
}